// Round 1
// baseline (6513.197 us; speedup 1.0000x reference)
//
#include <hip/hip_runtime.h>
#include <hip/hip_bf16.h>
#include <math.h>

typedef __hip_bfloat16 bf16;
typedef short v8s __attribute__((ext_vector_type(8)));
typedef float v4f __attribute__((ext_vector_type(4)));

#define NB   1024   // batch
#define NT   128    // encode steps
#define NDEC 64     // decode steps (incl. step 0 = last)
#define NH   128    // H
#define HE   256    // H_ENC
#define HD   132    // H_DEC
#define HDP  160    // padded K for decoder (5 * 32)
#define GDP  144    // padded per-gate col count for decoder (9 * 16)
#define NS   8      // elbo samples
#define SB   8192   // NS * NB
#define KX   32     // padded encoder input dim (2 + 16 -> 32)

namespace wsoff {
constexpr size_t al(size_t x){ return (x + 255) & ~size_t(255); }
constexpr size_t FLAG  = 0;
constexpr size_t XS    = 256;
constexpr size_t WIH0  = al(XS    + (size_t)NT*NB*KX*2);
constexpr size_t WHH0  = al(WIH0  + 768*32*2);
constexpr size_t WIH1  = al(WHH0  + 768*256*2);
constexpr size_t WHH1  = al(WIH1  + 768*256*2);
constexpr size_t BIH0  = al(WHH1  + 768*256*2);
constexpr size_t BHH0  = al(BIH0  + 768*4);
constexpr size_t BIH1  = al(BHH0  + 768*4);
constexpr size_t BHH1  = al(BIH1  + 768*4);
constexpr size_t WDHH0 = al(BHH1  + 768*4);
constexpr size_t WDIH1 = al(WDHH0 + 432*160*2);
constexpr size_t WDHH1 = al(WDIH1 + 432*160*2);
constexpr size_t WDIH0F= al(WDHH1 + 432*160*2);
constexpr size_t BDIH0 = al(WDIH0F+ 792*4);
constexpr size_t BDHH0 = al(BDIH0 + 396*4);
constexpr size_t BDIH1 = al(BDHH0 + 396*4);
constexpr size_t BDHH1 = al(BDIH1 + 396*4);
constexpr size_t W1B   = al(BDHH1 + 396*4);
constexpr size_t B1F   = al(W1B   + 64*128*2);
constexpr size_t W2F   = al(B1F   + 64*4);
constexpr size_t B2F   = al(W2F   + 128*4);
constexpr size_t H0F0  = al(B2F   + 2*4);
constexpr size_t H0F1  = al(H0F0  + (size_t)NB*HE*4);
constexpr size_t H0B0  = al(H0F1  + (size_t)NB*HE*4);
constexpr size_t H0B1  = al(H0B0  + (size_t)NB*HE*2);
constexpr size_t H1F0  = al(H0B1  + (size_t)NB*HE*2);
constexpr size_t H1F1  = al(H1F0  + (size_t)NB*HE*4);
constexpr size_t H1B0  = al(H1F1  + (size_t)NB*HE*4);
constexpr size_t H1B1  = al(H1B0  + (size_t)NB*HE*2);
constexpr size_t ENCP  = al(H1B1  + (size_t)NB*HE*2);        // fp32 [128*1024][2], row = t*NB + b
constexpr size_t DH0F0 = al(ENCP  + (size_t)NB*NT*2*4);
constexpr size_t DH0F1 = al(DH0F0 + (size_t)SB*HDP*4);
constexpr size_t DH0B0 = al(DH0F1 + (size_t)SB*HDP*4);
constexpr size_t DH0B1 = al(DH0B0 + (size_t)SB*HDP*2);
constexpr size_t DH1F0 = al(DH0B1 + (size_t)SB*HDP*2);
constexpr size_t DH1F1 = al(DH1F0 + (size_t)SB*HDP*4);
constexpr size_t DH1B0 = al(DH1F1 + (size_t)SB*HDP*4);
constexpr size_t DH1B1 = al(DH1B0 + (size_t)SB*HDP*2);
constexpr size_t INP   = al(DH1B1 + (size_t)SB*HDP*2);       // fp32 [SB][2]
constexpr size_t HIST  = al(INP   + (size_t)SB*2*4);         // fp32 [64][SB][2]
}

// ---------- device helpers ----------
__device__ __forceinline__ float ld_any(const void* p, size_t i, int isbf){
  return isbf ? __bfloat162float(((const bf16*)p)[i]) : ((const float*)p)[i];
}
__device__ __forceinline__ float sigm(float x){ return 1.0f/(1.0f+expf(-x)); }
__device__ __forceinline__ float softplusf(float x){ return x>20.f ? x : log1pf(expf(x)); }
__device__ __forceinline__ v4f mfma16(v8s a, v8s b, v4f c){
  return __builtin_amdgcn_mfma_f32_16x16x32_bf16(a,b,c,0,0,0);
}
__device__ __forceinline__ v8s fragld(const bf16* base, size_t elem_off){
  return *reinterpret_cast<const v8s*>(base + elem_off);
}
__device__ __forceinline__ float*  f32p(char* ws, size_t off){ return (float*)(ws+off); }
__device__ __forceinline__ bf16*   bfp (char* ws, size_t off){ return (bf16*)(ws+off); }
__device__ __forceinline__ float*  H0Fp(char* ws,int p){ return f32p(ws, p?wsoff::H0F1:wsoff::H0F0); }
__device__ __forceinline__ bf16*   H0Bp(char* ws,int p){ return bfp (ws, p?wsoff::H0B1:wsoff::H0B0); }
__device__ __forceinline__ float*  H1Fp(char* ws,int p){ return f32p(ws, p?wsoff::H1F1:wsoff::H1F0); }
__device__ __forceinline__ bf16*   H1Bp(char* ws,int p){ return bfp (ws, p?wsoff::H1B1:wsoff::H1B0); }
__device__ __forceinline__ float*  DH0Fp(char* ws,int p){ return f32p(ws, p?wsoff::DH0F1:wsoff::DH0F0); }
__device__ __forceinline__ bf16*   DH0Bp(char* ws,int p){ return bfp (ws, p?wsoff::DH0B1:wsoff::DH0B0); }
__device__ __forceinline__ float*  DH1Fp(char* ws,int p){ return f32p(ws, p?wsoff::DH1F1:wsoff::DH1F0); }
__device__ __forceinline__ bf16*   DH1Bp(char* ws,int p){ return bfp (ws, p?wsoff::DH1B1:wsoff::DH1B0); }

// ---------- dtype detection ----------
__global__ void k_detect(char* ws, const void* eps){
  const unsigned short* p = (const unsigned short*)eps;
  int lane = threadIdx.x;
  unsigned short u = p[2*lane];        // even uint16: bf16 element if bf16, fp32 low-mantissa if fp32
  int e = (u>>7)&0xFF;
  bool pl = (e>=118 && e<=130);        // plausible bf16 N(0,1) magnitude
  unsigned long long m = __ballot(pl);
  if (lane==0) *(int*)(ws+wsoff::FLAG) = (__popcll(m) >= 32) ? 1 : 0;
}

// ---------- staging ----------
__global__ void k_stage_xs(char* ws, const void* x, const void* feat){
  int isbf = *(const int*)(ws+wsoff::FLAG);
  size_t i = (size_t)blockIdx.x*blockDim.x + threadIdx.x;
  if (i >= (size_t)NT*NB*KX) return;
  int c = i % KX; size_t q = i / KX; int b = q % NB; int t = q / NB;
  float v = 0.f;
  if (c < 2)        v = ld_any(x,    ((size_t)b*NT + t)*2 + c, isbf);
  else if (c < 18)  v = ld_any(feat, ((size_t)b*192 + t)*16 + (c-2), isbf);
  ((bf16*)(ws+wsoff::XS))[i] = __float2bfloat16(v);
}
__global__ void k_stage_pad(char* ws, const void* src, size_t dstoff, int R, int SC, int DC){
  int isbf = *(const int*)(ws+wsoff::FLAG);
  size_t i = (size_t)blockIdx.x*blockDim.x + threadIdx.x;
  if (i >= (size_t)R*DC) return;
  int r = i / DC, c = i % DC;
  float v = (c < SC) ? ld_any(src, (size_t)r*SC + c, isbf) : 0.f;
  ((bf16*)(ws+dstoff))[i] = __float2bfloat16(v);
}
__global__ void k_stage_dec(char* ws, const void* src, size_t dstoff){
  int isbf = *(const int*)(ws+wsoff::FLAG);
  size_t i = (size_t)blockIdx.x*blockDim.x + threadIdx.x;
  if (i >= (size_t)432*HDP) return;
  int R = i / HDP, c = i % HDP;
  int g = R / GDP, ii = R % GDP;
  float v = (ii < HD && c < HD) ? ld_any(src, ((size_t)(g*HD+ii))*HD + c, isbf) : 0.f;
  ((bf16*)(ws+dstoff))[i] = __float2bfloat16(v);
}
__global__ void k_stage_f32(char* ws, const void* src, size_t dstoff, int n){
  int isbf = *(const int*)(ws+wsoff::FLAG);
  int i = blockIdx.x*blockDim.x + threadIdx.x;
  if (i >= n) return;
  ((float*)(ws+dstoff))[i] = ld_any(src, i, isbf);
}

// ---------- MLP tile (16 rows): softplus(relu(A@W1^T+b1)@W2^T+b2) ----------
__device__ void mlp_tile(char* ws, const bf16* A, int strideA, int rowbase,
                         const int* mask, int tcol, float* out1, float* out2, float* lds)
{
  const int lane = threadIdx.x, lr = lane&15, q = lane>>4;
  const bf16* W1 = (const bf16*)(ws+wsoff::W1B);
  const float* b1 = (const float*)(ws+wsoff::B1F);
  const float* W2 = (const float*)(ws+wsoff::W2F);
  const float* b2 = (const float*)(ws+wsoff::B2F);
  v4f acc[4];
  #pragma unroll
  for (int c=0;c<4;c++) acc[c] = (v4f){0.f,0.f,0.f,0.f};
  const int rowA = rowbase + lr;
  const bool valid = mask ? (mask[(size_t)rowA*NT + tcol] != 0) : true;
  #pragma unroll
  for (int kb=0;kb<4;kb++){
    const int ko = kb*32 + q*8;
    v8s a;
    if (valid) a = fragld(A, (size_t)rowA*strideA + ko);
    else       a = (v8s){0,0,0,0,0,0,0,0};
    #pragma unroll
    for (int c=0;c<4;c++){
      v8s b = fragld(W1, (size_t)(c*16+lr)*NH + ko);
      acc[c] = mfma16(a,b,acc[c]);
    }
  }
  #pragma unroll
  for (int c=0;c<4;c++){
    const int col = c*16+lr;
    #pragma unroll
    for (int r=0;r<4;r++){
      const int rt = q*4+r;
      float hv = acc[c][r] + b1[col];
      lds[rt*68+col] = hv>0.f ? hv : 0.f;
    }
  }
  __syncthreads();
  if (lane < 32){
    int row = lane>>1, oc = lane&1;
    float s = b2[oc];
    #pragma unroll 8
    for (int k2=0;k2<64;k2++) s += lds[row*68+k2]*W2[oc*64+k2];
    s = softplusf(s);
    size_t ro = (size_t)(rowbase+row)*2 + oc;
    out1[ro] = s;
    if (out2) out2[ro] = s;
  }
}

// ---------- encoder GRU step (one 16-row x 64-col block of one layer) ----------
__device__ void enc_gru_step(char* ws, const int* mask, int step, int id,
    const bf16* Ax, int sx, int kxSteps, const bf16* Wx,
    const bf16* Ah, const bf16* Wh,
    const float* bih, const float* bhh,
    const float* hfOld, float* hfNew, bf16* hbNew)
{
  const int lane = threadIdx.x, lr = lane&15, q = lane>>4;
  const int rb = id >> 2, cb = id & 3;
  v4f ax[3][4], ah[3][4];
  #pragma unroll
  for (int g=0;g<3;g++)
    #pragma unroll
    for (int c=0;c<4;c++){ ax[g][c]=(v4f){0.f,0.f,0.f,0.f}; ah[g][c]=(v4f){0.f,0.f,0.f,0.f}; }
  const size_t arow = (size_t)(rb*16 + lr);
  // input GEMM (K = sx*kxSteps... enc0: K=32 over Xs; enc1: K=256 over h0_new)
  for (int kb=0;kb<kxSteps;kb++){
    const int ko = kb*32 + q*8;
    v8s a = fragld(Ax, arow*sx + ko);
    #pragma unroll
    for (int g=0;g<3;g++)
      #pragma unroll
      for (int c=0;c<4;c++){
        v8s b = fragld(Wx, (size_t)(g*HE + cb*64 + c*16 + lr)*sx + ko);
        ax[g][c] = mfma16(a,b,ax[g][c]);
      }
  }
  // hidden GEMM (K=256)
  for (int kb=0;kb<8;kb++){
    const int ko = kb*32 + q*8;
    v8s a = fragld(Ah, arow*HE + ko);
    #pragma unroll
    for (int g=0;g<3;g++)
      #pragma unroll
      for (int c=0;c<4;c++){
        v8s b = fragld(Wh, (size_t)(g*HE + cb*64 + c*16 + lr)*HE + ko);
        ah[g][c] = mfma16(a,b,ah[g][c]);
      }
  }
  // fused GRU epilogue with masking
  #pragma unroll
  for (int c=0;c<4;c++){
    const int d = cb*64 + c*16 + lr;
    const float bir = bih[d]+bhh[d];
    const float biz = bih[HE+d]+bhh[HE+d];
    const float bin = bih[2*HE+d];
    const float bhn = bhh[2*HE+d];
    #pragma unroll
    for (int r=0;r<4;r++){
      const int row = rb*16 + q*4 + r;
      float rr = sigm(ax[0][c][r]+ah[0][c][r]+bir);
      float zz = sigm(ax[1][c][r]+ah[1][c][r]+biz);
      float nn = tanhf(ax[2][c][r]+bin + rr*(ah[2][c][r]+bhn));
      float ho = hfOld[(size_t)row*HE + d];
      float hv = (1.f-zz)*nn + zz*ho;
      float hout = mask[(size_t)row*NT + step] ? hv : ho;
      hfNew[(size_t)row*HE+d] = hout;
      hbNew[(size_t)row*HE+d] = __float2bfloat16(hout);
    }
  }
}

// ---------- encoder phase: layer0(t) | layer1(t-1) | mlp(t-2), one launch ----------
__global__ __launch_bounds__(64,1) void k_enc_phase(char* ws, const int* mask, int t){
  __shared__ float lds[16*68];
  const int id = blockIdx.x;
  if (id < 256){
    if (t > 127) return;
    enc_gru_step(ws, mask, t, id,
      bfp(ws,wsoff::XS) + (size_t)t*NB*KX, KX, 1, bfp(ws,wsoff::WIH0),
      H0Bp(ws,t&1), bfp(ws,wsoff::WHH0),
      f32p(ws,wsoff::BIH0), f32p(ws,wsoff::BHH0),
      H0Fp(ws,t&1), H0Fp(ws,(t+1)&1), H0Bp(ws,(t+1)&1));
  } else if (id < 512){
    const int step = t-1; if (step < 0 || step > 127) return;
    enc_gru_step(ws, mask, step, id-256,
      H0Bp(ws,(step+1)&1), HE, 8, bfp(ws,wsoff::WIH1),
      H1Bp(ws,step&1), bfp(ws,wsoff::WHH1),
      f32p(ws,wsoff::BIH1), f32p(ws,wsoff::BHH1),
      H1Fp(ws,step&1), H1Fp(ws,(step+1)&1), H1Bp(ws,(step+1)&1));
  } else {
    const int step = t-2; if (step < 0) return;
    float* out1 = f32p(ws,wsoff::ENCP) + (size_t)step*NB*2;
    mlp_tile(ws, H1Bp(ws,(step+1)&1), HE, (id-512)*16, mask, step, out1, nullptr, lds);
  }
}

// ---------- decoder init: z = eps*exp(0.5*logvar)+mean, fc, inp=last ----------
__global__ void k_dec_init(char* ws, const void* eps, const void* feat){
  int isbf = *(const int*)(ws+wsoff::FLAG);
  size_t idx = (size_t)blockIdx.x*blockDim.x + threadIdx.x;
  const size_t N1 = 2ull*SB*HDP;
  if (idx < N1){
    int l = (int)(idx / ((size_t)SB*HDP)); size_t rem = idx % ((size_t)SB*HDP);
    int row = (int)(rem / HDP); int d = (int)(rem % HDP);
    int s = row >> 10, b = row & 1023;
    const float* hT = f32p(ws, l ? wsoff::H1F0 : wsoff::H0F0);
    float v;
    if (d < NH){
      float mean = hT[(size_t)b*HE + d];
      float lv   = hT[(size_t)b*HE + NH + d];
      float e = ld_any(eps, ((size_t)(s*2+l)*NB + b)*NH + d, isbf);
      v = e*expf(0.5f*lv) + mean;
    } else if (d < HD){
      v = ld_any(feat, (size_t)b*192*16 + 128*16 + (d-NH), isbf);
    } else v = 0.f;
    f32p(ws, l?wsoff::DH1F0:wsoff::DH0F0)[rem] = v;
    bfp (ws, l?wsoff::DH1B0:wsoff::DH0B0)[rem] = __float2bfloat16(v);
  } else if (idx < N1 + (size_t)SB*2){
    size_t qq = idx - N1; int row = (int)(qq>>1); int c = (int)(qq&1); int b = row & 1023;
    float v = f32p(ws,wsoff::ENCP)[(size_t)(127*NB + b)*2 + c];
    f32p(ws,wsoff::INP)[qq]  = v;
    f32p(ws,wsoff::HIST)[qq] = v;   // hist[0] = last
  }
}

// ---------- decoder layer0 step ----------
__global__ __launch_bounds__(64,1) void k_dec0(char* ws, int k){
  const int lane = threadIdx.x, lr = lane&15, q = lane>>4;
  const int rb = blockIdx.x/3, by = blockIdx.x%3;
  v4f ah[3][3];
  #pragma unroll
  for (int g=0;g<3;g++)
    #pragma unroll
    for (int c=0;c<3;c++) ah[g][c]=(v4f){0.f,0.f,0.f,0.f};
  const bf16* Ah = DH0Bp(ws,k&1);
  const bf16* W  = bfp(ws,wsoff::WDHH0);
  const size_t arow = (size_t)(rb*16+lr)*HDP;
  #pragma unroll
  for (int kb=0;kb<5;kb++){
    const int ko = kb*32 + q*8;
    v8s a = fragld(Ah, arow + ko);
    #pragma unroll
    for (int g=0;g<3;g++)
      #pragma unroll
      for (int c=0;c<3;c++){
        v8s b = fragld(W, (size_t)(g*GDP + by*48 + c*16 + lr)*HDP + ko);
        ah[g][c] = mfma16(a,b,ah[g][c]);
      }
  }
  const float* WIH = f32p(ws,wsoff::WDIH0F);
  const float* bi  = f32p(ws,wsoff::BDIH0);
  const float* bh  = f32p(ws,wsoff::BDHH0);
  const float* inp = f32p(ws,wsoff::INP);
  const float* hfOld = DH0Fp(ws,k&1);
  float* hfNew = DH0Fp(ws,(k+1)&1);
  bf16*  hbNew = DH0Bp(ws,(k+1)&1);
  #pragma unroll
  for (int c=0;c<3;c++){
    const int d = by*48 + c*16 + lr;
    if (d >= HD) continue;
    const float wr0=WIH[(0*HD+d)*2], wr1=WIH[(0*HD+d)*2+1];
    const float wz0=WIH[(1*HD+d)*2], wz1=WIH[(1*HD+d)*2+1];
    const float wn0=WIH[(2*HD+d)*2], wn1=WIH[(2*HD+d)*2+1];
    const float bir=bi[d], bhr=bh[d], biz=bi[HD+d], bhz=bh[HD+d], bin=bi[2*HD+d], bhn=bh[2*HD+d];
    #pragma unroll
    for (int r=0;r<4;r++){
      const int row = rb*16 + q*4 + r;
      const float i0 = inp[(size_t)row*2], i1 = inp[(size_t)row*2+1];
      float rr = sigm(i0*wr0+i1*wr1+bir + ah[0][c][r] + bhr);
      float zz = sigm(i0*wz0+i1*wz1+biz + ah[1][c][r] + bhz);
      float nn = tanhf(i0*wn0+i1*wn1+bin + rr*(ah[2][c][r]+bhn));
      float ho = hfOld[(size_t)row*HDP + d];
      float hv = (1.f-zz)*nn + zz*ho;
      hfNew[(size_t)row*HDP+d] = hv;
      hbNew[(size_t)row*HDP+d] = __float2bfloat16(hv);
    }
  }
}

// ---------- decoder layer1 step ----------
__global__ __launch_bounds__(64,1) void k_dec1(char* ws, int k){
  const int lane = threadIdx.x, lr = lane&15, q = lane>>4;
  const int rb = blockIdx.x/3, by = blockIdx.x%3;
  v4f ax[3][3], ah[3][3];
  #pragma unroll
  for (int g=0;g<3;g++)
    #pragma unroll
    for (int c=0;c<3;c++){ ax[g][c]=(v4f){0.f,0.f,0.f,0.f}; ah[g][c]=(v4f){0.f,0.f,0.f,0.f}; }
  const bf16* Ax = DH0Bp(ws,(k+1)&1);
  const bf16* Wx = bfp(ws,wsoff::WDIH1);
  const bf16* Ah = DH1Bp(ws,k&1);
  const bf16* Wh = bfp(ws,wsoff::WDHH1);
  const size_t arow = (size_t)(rb*16+lr)*HDP;
  #pragma unroll
  for (int kb=0;kb<5;kb++){
    const int ko = kb*32 + q*8;
    v8s a1 = fragld(Ax, arow + ko);
    v8s a2 = fragld(Ah, arow + ko);
    #pragma unroll
    for (int g=0;g<3;g++)
      #pragma unroll
      for (int c=0;c<3;c++){
        const size_t wr = (size_t)(g*GDP + by*48 + c*16 + lr)*HDP + ko;
        ax[g][c] = mfma16(a1, fragld(Wx,wr), ax[g][c]);
        ah[g][c] = mfma16(a2, fragld(Wh,wr), ah[g][c]);
      }
  }
  const float* bi = f32p(ws,wsoff::BDIH1);
  const float* bh = f32p(ws,wsoff::BDHH1);
  const float* hfOld = DH1Fp(ws,k&1);
  float* hfNew = DH1Fp(ws,(k+1)&1);
  bf16*  hbNew = DH1Bp(ws,(k+1)&1);
  #pragma unroll
  for (int c=0;c<3;c++){
    const int d = by*48 + c*16 + lr;
    if (d >= HD) continue;
    const float bir=bi[d]+bh[d], biz=bi[HD+d]+bh[HD+d], bin=bi[2*HD+d], bhn=bh[2*HD+d];
    #pragma unroll
    for (int r=0;r<4;r++){
      const int row = rb*16 + q*4 + r;
      float rr = sigm(ax[0][c][r]+ah[0][c][r]+bir);
      float zz = sigm(ax[1][c][r]+ah[1][c][r]+biz);
      float nn = tanhf(ax[2][c][r]+bin + rr*(ah[2][c][r]+bhn));
      float ho = hfOld[(size_t)row*HDP + d];
      float hv = (1.f-zz)*nn + zz*ho;
      hfNew[(size_t)row*HDP+d] = hv;
      hbNew[(size_t)row*HDP+d] = __float2bfloat16(hv);
    }
  }
}

// ---------- standalone MLP (decoder) ----------
__global__ __launch_bounds__(64,1) void k_mlp(char* ws, const bf16* A, int strideA,
                                              float* out1, float* out2){
  __shared__ float lds[16*68];
  mlp_tile(ws, A, strideA, blockIdx.x*16, nullptr, 0, out1, out2, lds);
}

// ---------- final output assembly ----------
__global__ void k_assemble(char* ws, void* out){
  int isbf = *(const int*)(ws+wsoff::FLAG);
  const float* encp = f32p(ws,wsoff::ENCP);
  const float* hist = f32p(ws,wsoff::HIST);
  const size_t N0 = (size_t)NS*NB*127*2;
  const size_t NTOT = N0 + (size_t)NS*NB*NDEC*2;
  for (size_t i = (size_t)blockIdx.x*blockDim.x + threadIdx.x; i < NTOT;
       i += (size_t)gridDim.x*blockDim.x){
    float v;
    if (i < N0){
      int c = (int)(i & 1); size_t qq = i >> 1;
      int tt = (int)(qq % 127); size_t q2 = qq / 127; int b = (int)(q2 & 1023);
      v = encp[((size_t)tt*NB + b)*2 + c];
    } else {
      size_t j = i - N0; int c = (int)(j & 1); size_t qq = j >> 1;
      int kk = (int)(qq & 63); size_t sb = qq >> 6;
      v = hist[((size_t)kk*SB + sb)*2 + c];
    }
    if (isbf) ((bf16*)out)[i] = __float2bfloat16(v);
    else      ((float*)out)[i] = v;
  }
}

extern "C" void kernel_launch(void* const* d_in, const int* in_sizes, int n_in,
                              void* d_out, int out_size, void* d_ws, size_t ws_size,
                              hipStream_t stream) {
  char* ws = (char*)d_ws;
  const int* mask = (const int*)d_in[2];
  auto gb = [](size_t n){ return dim3((unsigned)((n + 255)/256)); };

  // zero the initial-state buffers (ws is re-poisoned before every call)
  hipMemsetAsync(ws+wsoff::H0F0, 0, (size_t)NB*HE*4, stream);
  hipMemsetAsync(ws+wsoff::H0B0, 0, (size_t)NB*HE*2, stream);
  hipMemsetAsync(ws+wsoff::H1F0, 0, (size_t)NB*HE*4, stream);
  hipMemsetAsync(ws+wsoff::H1B0, 0, (size_t)NB*HE*2, stream);
  hipMemsetAsync(ws+wsoff::DH0B1, 0, (size_t)SB*HDP*2, stream);  // keep K-pad zero
  hipMemsetAsync(ws+wsoff::DH1B1, 0, (size_t)SB*HDP*2, stream);

  k_detect<<<1,64,0,stream>>>(ws, d_in[3]);

  // stage inputs / weights (bf16 for MFMA, fp32 for epilogues)
  k_stage_xs <<<gb((size_t)NT*NB*KX),256,0,stream>>>(ws, d_in[0], d_in[1]);
  k_stage_pad<<<gb(768*32) ,256,0,stream>>>(ws, d_in[7],  wsoff::WIH0, 768, 18, 32);
  k_stage_pad<<<gb(768*256),256,0,stream>>>(ws, d_in[8],  wsoff::WHH0, 768, 256, 256);
  k_stage_pad<<<gb(768*256),256,0,stream>>>(ws, d_in[11], wsoff::WIH1, 768, 256, 256);
  k_stage_pad<<<gb(768*256),256,0,stream>>>(ws, d_in[12], wsoff::WHH1, 768, 256, 256);
  k_stage_pad<<<gb(64*128) ,256,0,stream>>>(ws, d_in[23], wsoff::W1B,  64, 128, 128);
  k_stage_dec<<<gb(432*160),256,0,stream>>>(ws, d_in[16], wsoff::WDHH0);
  k_stage_dec<<<gb(432*160),256,0,stream>>>(ws, d_in[19], wsoff::WDIH1);
  k_stage_dec<<<gb(432*160),256,0,stream>>>(ws, d_in[20], wsoff::WDHH1);
  k_stage_f32<<<gb(768),256,0,stream>>>(ws, d_in[9],  wsoff::BIH0, 768);
  k_stage_f32<<<gb(768),256,0,stream>>>(ws, d_in[10], wsoff::BHH0, 768);
  k_stage_f32<<<gb(768),256,0,stream>>>(ws, d_in[13], wsoff::BIH1, 768);
  k_stage_f32<<<gb(768),256,0,stream>>>(ws, d_in[14], wsoff::BHH1, 768);
  k_stage_f32<<<gb(792),256,0,stream>>>(ws, d_in[15], wsoff::WDIH0F, 792);
  k_stage_f32<<<gb(396),256,0,stream>>>(ws, d_in[17], wsoff::BDIH0, 396);
  k_stage_f32<<<gb(396),256,0,stream>>>(ws, d_in[18], wsoff::BDHH0, 396);
  k_stage_f32<<<gb(396),256,0,stream>>>(ws, d_in[21], wsoff::BDIH1, 396);
  k_stage_f32<<<gb(396),256,0,stream>>>(ws, d_in[22], wsoff::BDHH1, 396);
  k_stage_f32<<<gb(64) ,256,0,stream>>>(ws, d_in[24], wsoff::B1F, 64);
  k_stage_f32<<<gb(128),256,0,stream>>>(ws, d_in[25], wsoff::W2F, 128);
  k_stage_f32<<<gb(2)  ,256,0,stream>>>(ws, d_in[26], wsoff::B2F, 2);

  // encoder: software-pipelined phases (layer0 t | layer1 t-1 | mlp t-2)
  for (int t = 0; t <= 129; ++t)
    k_enc_phase<<<576,64,0,stream>>>(ws, mask, t);

  // decoder init
  {
    size_t N = 2ull*SB*HDP + (size_t)SB*2;
    k_dec_init<<<gb(N),256,0,stream>>>(ws, d_in[3], d_in[1]);
  }

  // decoder: 63 steps of d0 -> d1 -> mlp
  for (int k = 0; k < 63; ++k){
    k_dec0<<<1536,64,0,stream>>>(ws, k);
    k_dec1<<<1536,64,0,stream>>>(ws, k);
    const bf16* A = (const bf16*)(ws + (((k+1)&1) ? wsoff::DH1B1 : wsoff::DH1B0));
    float* o1 = (float*)(ws+wsoff::HIST) + (size_t)(k+1)*SB*2;
    float* o2 = (float*)(ws+wsoff::INP);
    k_mlp<<<SB/16,64,0,stream>>>(ws, A, HDP, o1, o2);
  }

  k_assemble<<<4096,256,0,stream>>>(ws, d_out);
}